// Round 6
// baseline (4511.570 us; speedup 1.0000x reference)
//
#include <hip/hip_runtime.h>
#include <hip/hip_bf16.h>
#include <math.h>

// Problem constants
#define NTOK  65536      // B*T
#define CDIM  512
#define NHEAD 8
#define HSZ   64
#define NLAYER 6
#define DFF   2048
#define VOCAB 65

typedef unsigned short u16;
typedef __attribute__((ext_vector_type(8))) __bf16 bf16x8;
typedef __attribute__((ext_vector_type(4))) float f32x4;
typedef __attribute__((ext_vector_type(8))) unsigned short ushort8;

__device__ __forceinline__ float b2f(u16 u) {
    union { unsigned int i; float f; } x; x.i = ((unsigned int)u) << 16; return x.f;
}
__device__ __forceinline__ u16 f2b(float f) {
    union { float f; unsigned int i; } x; x.f = f;
    unsigned int r = x.i + 0x7fffu + ((x.i >> 16) & 1u);   // RNE
    return (u16)(r >> 16);
}

__device__ __forceinline__ void async16(const u16* g, u16* l) {
    __builtin_amdgcn_global_load_lds(
        (const __attribute__((address_space(1))) void*)g,
        (__attribute__((address_space(3))) void*)l, 16, 0, 0);
}

// ---------------------------------------------------------------------------
// GEMM: C[M x N] = A[M x K] @ Bt[N x K]^T   (A,Bt bf16; fp32 MFMA accum)
// EPI: 0 plain->bf16, 2 relu(+bias)->bf16, 3 +bias->f32 masked col<Nout
// R4's measured-best structure: 256x128 tile, 512 thr (8 waves, 64x64 each),
// BK=64 two-barrier K-loop (R5's single-barrier dbuf REGRESSED: __syncthreads
// drains vmcnt(0), so prefetch can't cross the barrier; BK=64 amortizes one
// ~900cyc HBM drain over 620cyc of MFMA). Swapped-operand MFMA epilogue:
// lane holds 4 consecutive N-cols -> 8B vector stores.
// XCD swizzle: id%8 = XCD owns whole m-stripes. Requires gridDim.y % 8 == 0.
// ---------------------------------------------------------------------------
template<int EPI>
__global__ __launch_bounds__(512)
void gemm_bt(const u16* __restrict__ A, const u16* __restrict__ Bt,
             void* __restrict__ Cout, const float* __restrict__ bias,
             int K, int N, int Nout)
{
    __shared__ u16 lA[2 * 256 * 32];   // [panel][row<256][32]  32 KB
    __shared__ u16 lB[2 * 128 * 32];   // [panel][row<128][32]  16 KB
    const int tid  = threadIdx.x;

    // XCD-aware swizzle
    const int Nx = gridDim.x;
    const int id = blockIdx.y * Nx + blockIdx.x;
    const int xcd = id & 7;
    const int j0  = id >> 3;
    const int mt  = xcd + 8 * (j0 / Nx);
    const int nt  = j0 - (j0 / Nx) * Nx;
    const int m0  = mt * 256;
    const int n0  = nt * 128;

    const int lane = tid & 63;
    const int wv   = tid >> 6;         // 0..7
    const int wr   = (wv >> 1) * 64;   // wave row offset (0,64,128,192)
    const int wc   = (wv & 1) * 64;    // wave col offset (0,64)
    const int r16  = lane & 15;
    const int quad = lane >> 4;

    f32x4 acc[4][4] = {};              // acc[j][i], swapped-operand layout

    const int srow = tid >> 2, skseg = (tid & 3) * 8;
    const u16* pA  = A  + (size_t)(m0 + srow) * K + skseg;   // rows 0..127
    const u16* pA2 = pA + (size_t)128 * K;                   // rows 128..255
    const u16* pB  = Bt + (size_t)(n0 + srow) * K + skseg;
    u16* lAt = &lA[(size_t)tid * 8];
    u16* lBt = &lB[(size_t)tid * 8];

    for (int k0 = 0; k0 < K; k0 += 64) {
        async16(pA  + k0,      lAt);            // panel0 rows 0..127
        async16(pA2 + k0,      lAt + 4096);     // panel0 rows 128..255
        async16(pA  + k0 + 32, lAt + 8192);     // panel1 rows 0..127
        async16(pA2 + k0 + 32, lAt + 12288);    // panel1 rows 128..255
        async16(pB  + k0,      lBt);            // panel0
        async16(pB  + k0 + 32, lBt + 4096);     // panel1
        __syncthreads();   // drains vmcnt -> LDS valid

#pragma unroll
        for (int s = 0; s < 2; s++) {
            const u16* bA = &lA[s * 8192];
            const u16* bB = &lB[s * 4096];
            bf16x8 af[4], bfr[4];
#pragma unroll
            for (int i = 0; i < 4; i++)
                af[i] = *(const bf16x8*)(const void*)&bA[(wr + i * 16 + r16) * 32 + quad * 8];
#pragma unroll
            for (int j = 0; j < 4; j++)
                bfr[j] = *(const bf16x8*)(const void*)&bB[(wc + j * 16 + r16) * 32 + quad * 8];
#pragma unroll
            for (int j = 0; j < 4; j++)
#pragma unroll
                for (int i = 0; i < 4; i++)
                    acc[j][i] = __builtin_amdgcn_mfma_f32_16x16x32_bf16(bfr[j], af[i], acc[j][i], 0, 0, 0);
        }
        __syncthreads();   // all reads done before next stage overwrites
    }

    // epilogue (swapped layout): row = wr+i*16+r16, cols = wc+j*16+quad*4+r
#pragma unroll
    for (int i = 0; i < 4; i++) {
        const int row = m0 + wr + i * 16 + r16;
#pragma unroll
        for (int j = 0; j < 4; j++) {
            const int colb = n0 + wc + j * 16 + quad * 4;
            float v[4];
#pragma unroll
            for (int r = 0; r < 4; r++) v[r] = acc[j][i][r];
            if (EPI == 2) {
                const f32x4 b4 = *(const f32x4*)(const void*)&bias[colb];
#pragma unroll
                for (int r = 0; r < 4; r++) v[r] = fmaxf(v[r] + b4[r], 0.f);
            }
            if (EPI == 3) {
#pragma unroll
                for (int r = 0; r < 4; r++) {
                    const int col = colb + r;
                    if (col < Nout)
                        ((float*)Cout)[(size_t)row * Nout + col] = v[r] + bias[col];
                }
            } else {
                uint2 o;
                o.x = (unsigned)f2b(v[0]) | ((unsigned)f2b(v[1]) << 16);
                o.y = (unsigned)f2b(v[2]) | ((unsigned)f2b(v[3]) << 16);
                *(uint2*)(void*)&((u16*)Cout)[(size_t)row * N + colb] = o;
            }
        }
    }
}

// ---------------------------------------------------------------------------
// Fused GEMM + bias + residual + LayerNorm, N = 512 (full rows per block).
// X[m][:] = LN( A[m][:K] @ Bt^T + bias + res[m][:] ) * g + be
// Tile 128x512, 512 thr = 8 waves (2 rgrp x 4 cgrp, each 64x128).
// acc[8][4] = 128 VGPR -> 2 waves/SIMD; LDS 84 KB -> 1 block/CU.
// res/X may alias (in-place): each block owns its rows exclusively.
// ---------------------------------------------------------------------------
__global__ __launch_bounds__(512, 2)
void gemm_ln(const u16* __restrict__ A, const u16* __restrict__ Bt,
             const float* __restrict__ bias, const u16* __restrict__ res,
             const float* __restrict__ g, const float* __restrict__ be,
             u16* __restrict__ X, int K)
{
    __shared__ u16 lA[2 * 128 * 32];   // 16 KB  [panel][row<128][32]
    __shared__ u16 lB[2 * 512 * 32];   // 64 KB  [panel][row<512][32]
    __shared__ float rsum[128][4];     // 2 KB   per-cgrp partial row sums
    __shared__ float rsq[128][4];      // 2 KB
    const int tid  = threadIdx.x;
    const int m0   = blockIdx.x * 128;
    const int lane = tid & 63;
    const int wv   = tid >> 6;          // 0..7
    const int wrow = (wv >> 2) * 64;    // 0,64
    const int wcol = (wv & 3) * 128;    // 0,128,256,384
    const int cg   = wv & 3;
    const int r16  = lane & 15;
    const int quad = lane >> 4;

    f32x4 acc[8][4] = {};               // [j][i] swapped-operand layout

    const int arow = tid >> 2, aseg = (tid & 3) * 8;
    const u16* pA = A  + (size_t)(m0 + arow) * K + aseg;
    const u16* pB = Bt + (size_t)arow * K + aseg;   // rows arow + i*128
    const size_t bK128 = (size_t)128 * K;
    u16* lAt = &lA[(size_t)tid * 8];
    u16* lBt = &lB[(size_t)tid * 8];

    for (int k0 = 0; k0 < K; k0 += 64) {
        async16(pA + k0,      lAt);           // panel0
        async16(pA + k0 + 32, lAt + 4096);    // panel1
#pragma unroll
        for (int i = 0; i < 4; i++) {
            async16(pB + i * bK128 + k0,      lBt + i * 4096);           // p0
            async16(pB + i * bK128 + k0 + 32, lBt + 16384 + i * 4096);   // p1
        }
        __syncthreads();

#pragma unroll
        for (int s = 0; s < 2; s++) {
            const u16* bA = &lA[s * 4096];
            const u16* bB = &lB[s * 16384];
            bf16x8 af[4], bfr[8];
#pragma unroll
            for (int i = 0; i < 4; i++)
                af[i] = *(const bf16x8*)(const void*)&bA[(wrow + i * 16 + r16) * 32 + quad * 8];
#pragma unroll
            for (int j = 0; j < 8; j++)
                bfr[j] = *(const bf16x8*)(const void*)&bB[(wcol + j * 16 + r16) * 32 + quad * 8];
#pragma unroll
            for (int j = 0; j < 8; j++)
#pragma unroll
                for (int i = 0; i < 4; i++)
                    acc[j][i] = __builtin_amdgcn_mfma_f32_16x16x32_bf16(bfr[j], af[i], acc[j][i], 0, 0, 0);
        }
        __syncthreads();
    }

    // ---- epilogue: y = acc + bias + res; block-wide row LN; write X ----
    float ps[4] = {0.f, 0.f, 0.f, 0.f}, pq[4] = {0.f, 0.f, 0.f, 0.f};
#pragma unroll
    for (int j = 0; j < 8; j++) {
        const int colb = wcol + j * 16 + quad * 4;
        const f32x4 b4 = *(const f32x4*)(const void*)&bias[colb];
#pragma unroll
        for (int i = 0; i < 4; i++) {
            const int row = m0 + wrow + i * 16 + r16;
            const uint2 rv = *(const uint2*)(const void*)&res[(size_t)row * 512 + colb];
            float v0 = acc[j][i][0] + b4[0] + b2f((u16)(rv.x & 0xffffu));
            float v1 = acc[j][i][1] + b4[1] + b2f((u16)(rv.x >> 16));
            float v2 = acc[j][i][2] + b4[2] + b2f((u16)(rv.y & 0xffffu));
            float v3 = acc[j][i][3] + b4[3] + b2f((u16)(rv.y >> 16));
            acc[j][i][0] = v0; acc[j][i][1] = v1;
            acc[j][i][2] = v2; acc[j][i][3] = v3;
            ps[i] += (v0 + v1) + (v2 + v3);
            pq[i] += (v0 * v0 + v1 * v1) + (v2 * v2 + v3 * v3);
        }
    }
    // reduce over quads (lanes r16+16q hold disjoint cols of the same rows)
#pragma unroll
    for (int i = 0; i < 4; i++) {
        ps[i] += __shfl_xor(ps[i], 16); ps[i] += __shfl_xor(ps[i], 32);
        pq[i] += __shfl_xor(pq[i], 16); pq[i] += __shfl_xor(pq[i], 32);
    }
    if (quad == 0) {
#pragma unroll
        for (int i = 0; i < 4; i++) {
            rsum[wrow + i * 16 + r16][cg] = ps[i];
            rsq [wrow + i * 16 + r16][cg] = pq[i];
        }
    }
    __syncthreads();
    float mu[4], rstd[4];
#pragma unroll
    for (int i = 0; i < 4; i++) {
        const int lr = wrow + i * 16 + r16;
        const float s = (rsum[lr][0] + rsum[lr][1]) + (rsum[lr][2] + rsum[lr][3]);
        const float q = (rsq[lr][0] + rsq[lr][1]) + (rsq[lr][2] + rsq[lr][3]);
        mu[i] = s * (1.f / 512.f);
        const float var = q * (1.f / 512.f) - mu[i] * mu[i];
        rstd[i] = rsqrtf(var + 1e-5f);
    }
#pragma unroll
    for (int j = 0; j < 8; j++) {
        const int colb = wcol + j * 16 + quad * 4;
        const f32x4 g4 = *(const f32x4*)(const void*)&g[colb];
        const f32x4 e4 = *(const f32x4*)(const void*)&be[colb];
#pragma unroll
        for (int i = 0; i < 4; i++) {
            const int row = m0 + wrow + i * 16 + r16;
            const float v0 = (acc[j][i][0] - mu[i]) * rstd[i] * g4[0] + e4[0];
            const float v1 = (acc[j][i][1] - mu[i]) * rstd[i] * g4[1] + e4[1];
            const float v2 = (acc[j][i][2] - mu[i]) * rstd[i] * g4[2] + e4[2];
            const float v3 = (acc[j][i][3] - mu[i]) * rstd[i] * g4[3] + e4[3];
            uint2 o;
            o.x = (unsigned)f2b(v0) | ((unsigned)f2b(v1) << 16);
            o.y = (unsigned)f2b(v2) | ((unsigned)f2b(v3) << 16);
            *(uint2*)(void*)&X[(size_t)row * 512 + colb] = o;
        }
    }
}

// ---------------------------------------------------------------------------
// Attention: one wave per (b,h). T=8, HS=64. qkv layout [token][q|k|v, h*64+d].
// NOTE: reference scale = C^-0.5 = 512^-0.5 (not HS^-0.5).
// ---------------------------------------------------------------------------
__global__ __launch_bounds__(256)
void attn_k(const u16* __restrict__ qkv, u16* __restrict__ out)
{
    __shared__ float sq[4][8][64], sk[4][8][64], sv[4][8][64], sp[4][64];
    const int w = threadIdx.x >> 6, lane = threadIdx.x & 63;
    const int unit = blockIdx.x * 4 + w;        // local b*8 + h
    const int b = unit >> 3, h = unit & 7;
    const size_t base = (size_t)b * 8 * 1536 + h * 64;
#pragma unroll
    for (int t = 0; t < 8; t++) {
        sq[w][t][lane] = b2f(qkv[base + t * 1536 + lane]);
        sk[w][t][lane] = b2f(qkv[base + t * 1536 + 512 + lane]);
        sv[w][t][lane] = b2f(qkv[base + t * 1536 + 1024 + lane]);
    }
    __syncthreads();
    const int t = lane >> 3, s = lane & 7;
    float sc = -1e30f;
    if (s <= t) {
        float d = 0.f;
#pragma unroll
        for (int c = 0; c < 64; c++) d += sq[w][t][c] * sk[w][s][c];
        sc = d * 0.04419417382415922f;          // 512^-0.5
    }
    float mx = sc;
#pragma unroll
    for (int m = 1; m < 8; m <<= 1) mx = fmaxf(mx, __shfl_xor(mx, m, 8));
    float e = __expf(sc - mx);
    if (s > t) e = 0.f;
    float sum = e;
#pragma unroll
    for (int m = 1; m < 8; m <<= 1) sum += __shfl_xor(sum, m, 8);
    sp[w][lane] = e / sum;
    __syncthreads();
#pragma unroll
    for (int tt = 0; tt < 8; tt++) {
        float a = 0.f;
#pragma unroll
        for (int ss = 0; ss < 8; ss++) a += sp[w][tt * 8 + ss] * sv[w][ss][lane];
        out[((size_t)b * 8 + tt) * 512 + h * 64 + lane] = f2b(a);
    }
}

// ---------------------------------------------------------------------------
// Embedding: block per token, x = tok_table[idx] + pos_table -> bf16
// ---------------------------------------------------------------------------
__global__ __launch_bounds__(256)
void embed_k(const int* __restrict__ idx, const float* __restrict__ tokt,
             const float* __restrict__ pos, u16* __restrict__ xb)
{
    const int tk = blockIdx.x;
    const int t = tk & 7;
    const int ix = idx[tk];
    const int c = threadIdx.x;
    const size_t o = (size_t)tk * 512;
    xb[o + c]       = f2b(tokt[(size_t)ix * 512 + c]       + pos[t * 512 + c]);
    xb[o + c + 256] = f2b(tokt[(size_t)ix * 512 + c + 256] + pos[t * 512 + c + 256]);
}

// ---------------------------------------------------------------------------
// Weight converts (fp32 -> bf16 B^T layouts), LDS-tiled transposes
// ---------------------------------------------------------------------------
__global__ __launch_bounds__(256)
void conv_t2_k(const float* __restrict__ in, u16* __restrict__ out, int K, int N)
{
    __shared__ float t[32][33];
    const int tx = threadIdx.x & 31, ty4 = (threadIdx.x >> 5) * 4;
    const int n0 = blockIdx.x * 32, k0 = blockIdx.y * 32, l = blockIdx.z;
    const size_t per = (size_t)K * N;
    const float* src = in + l * per;
#pragma unroll
    for (int r = 0; r < 4; r++)
        t[ty4 + r][tx] = src[(size_t)(k0 + ty4 + r) * N + n0 + tx];
    __syncthreads();
    u16* dst = out + l * per;
#pragma unroll
    for (int r = 0; r < 4; r++)
        dst[(size_t)(n0 + ty4 + r) * K + k0 + tx] = f2b(t[tx][ty4 + r]);
}

__global__ __launch_bounds__(256)
void conv_qkv2_k(const float* __restrict__ wq, const float* __restrict__ wk,
                 const float* __restrict__ wv, u16* __restrict__ out)
{
    __shared__ float t[32][33];
    const int tx = threadIdx.x & 31, ty4 = (threadIdx.x >> 5) * 4;
    const int c0 = blockIdx.x * 32, d0 = blockIdx.y * 32;
    const int z = blockIdx.z;
    const int sel = z / 48, rem = z - sel * 48;
    const int l = rem >> 3, h = rem & 7;
    const float* src = (sel == 0) ? wq : (sel == 1) ? wk : wv;
    const float* sb = src + (((size_t)l * 8 + h) * 512) * 64;
#pragma unroll
    for (int r = 0; r < 4; r++)
        t[ty4 + r][tx] = sb[(size_t)(c0 + ty4 + r) * 64 + d0 + tx];
    __syncthreads();
    u16* dst = out + (size_t)l * 786432 + (size_t)(sel * 512 + h * 64 + d0) * 512;
#pragma unroll
    for (int r = 0; r < 4; r++)
        dst[(size_t)(ty4 + r) * 512 + c0 + tx] = f2b(t[tx][ty4 + r]);
}

__global__ __launch_bounds__(256)
void conv_lm_k(const float* __restrict__ lm_w, u16* __restrict__ out)
{
    int gid = blockIdx.x * 256 + threadIdx.x;        // < 128*512
    int n = gid >> 9, c = gid & 511;
    out[gid] = (n < VOCAB) ? f2b(lm_w[(size_t)c * VOCAB + n]) : (u16)0;
}

// ---------------------------------------------------------------------------
extern "C" void kernel_launch(void* const* d_in, const int* in_sizes, int n_in,
                              void* d_out, int out_size, void* d_ws, size_t ws_size,
                              hipStream_t stream)
{
    const int*   idx    = (const int*)  d_in[0];
    const float* tokt   = (const float*)d_in[1];
    const float* post   = (const float*)d_in[2];
    const float* wq     = (const float*)d_in[3];
    const float* wk     = (const float*)d_in[4];
    const float* wvp    = (const float*)d_in[5];
    const float* proj_w = (const float*)d_in[6];
    const float* proj_b = (const float*)d_in[7];
    const float* w1     = (const float*)d_in[8];
    const float* b1     = (const float*)d_in[9];
    const float* w2     = (const float*)d_in[10];
    const float* b2     = (const float*)d_in[11];
    const float* ln1_g  = (const float*)d_in[12];
    const float* ln1_b  = (const float*)d_in[13];
    const float* ln2_g  = (const float*)d_in[14];
    const float* ln2_b  = (const float*)d_in[15];
    const float* lm_w   = (const float*)d_in[16];
    const float* lm_b   = (const float*)d_in[17];
    float* out = (float*)d_out;

    char* ws = (char*)d_ws;
    u16* wqkvt = (u16*)(ws + 0);                     //  9,437,184
    u16* wprjt = (u16*)(ws + 9437184);               //  3,145,728
    u16* ww1t  = (u16*)(ws + 12582912);              // 12,582,912
    u16* ww2t  = (u16*)(ws + 25165824);              // 12,582,912
    u16* wlmt  = (u16*)(ws + 37748736);              //    131,072
    u16* xb    = (u16*)(ws + 37879808);              // 67,108,864  residual
    char* big  = ws + 104988672;                     // chunk*4096 transient

    const size_t fixed_bytes = 104988672ull;
    int chunk = 4096;
    const int cands[4] = {65536, 32768, 16384, 8192};
    for (int i = 0; i < 4; i++) {
        if (fixed_bytes + (size_t)cands[i] * 4096ull <= ws_size) { chunk = cands[i]; break; }
    }
    const int nchunks = NTOK / chunk;
    u16* qkvc  = (u16*)big;                          // chunk x 1536
    u16* attnc = (u16*)(big + (size_t)chunk * 3072); // chunk x 512
    u16* h1c   = (u16*)big;                          // chunk x 2048

    conv_qkv2_k<<<dim3(16, 2, 144), 256, 0, stream>>>(wq, wk, wvp, wqkvt);
    conv_t2_k  <<<dim3(16, 16, 6), 256, 0, stream>>>(proj_w, wprjt, 512, 512);
    conv_t2_k  <<<dim3(64, 16, 6), 256, 0, stream>>>(w1, ww1t, 512, 2048);
    conv_t2_k  <<<dim3(16, 64, 6), 256, 0, stream>>>(w2, ww2t, 2048, 512);
    conv_lm_k  <<<128 * 512 / 256, 256, 0, stream>>>(lm_w, wlmt);

    embed_k<<<NTOK, 256, 0, stream>>>(idx, tokt, post, xb);

    for (int l = 0; l < NLAYER; l++) {
        // ---- attention phase, chunked over tokens ----
        for (int c = 0; c < nchunks; c++) {
            const size_t t0 = (size_t)c * chunk;
            // qkv = x @ Wqkv
            gemm_bt<0><<<dim3(12, chunk / 256), 512, 0, stream>>>(
                xb + t0 * 512, wqkvt + (size_t)l * 786432, qkvc,
                nullptr, 512, 1536, 1536);
            // attention (chunk-local)
            attn_k<<<chunk / 4, 256, 0, stream>>>(qkvc, attnc);
            // x = LN1(attno @ proj_w + proj_b + x)   (fused, in-place rows)
            gemm_ln<<<dim3(chunk / 128), 512, 0, stream>>>(
                attnc, wprjt + (size_t)l * 262144, proj_b + l * 512,
                xb + t0 * 512, ln1_g + l * 512, ln1_b + l * 512,
                xb + t0 * 512, 512);
        }
        // ---- MLP phase, chunked over tokens ----
        for (int c = 0; c < nchunks; c++) {
            const size_t t0 = (size_t)c * chunk;
            // h1 = relu(x @ w1 + b1)
            gemm_bt<2><<<dim3(16, chunk / 256), 512, 0, stream>>>(
                xb + t0 * 512, ww1t + (size_t)l * 1048576, h1c,
                b1 + l * 2048, 512, 2048, 2048);
            // x = LN2(h1 @ w2 + b2 + x)   (fused, in-place rows)
            gemm_ln<<<dim3(chunk / 128), 512, 0, stream>>>(
                h1c, ww2t + (size_t)l * 1048576, b2 + l * 512,
                xb + t0 * 512, ln2_g + l * 512, ln2_b + l * 512,
                xb + t0 * 512, 2048);
        }
    }

    // logits = x @ lm_w + lm_b  (N padded to 128, masked fp32 store)
    gemm_bt<3><<<dim3(1, 256), 512, 0, stream>>>(
        xb, wlmt, out, lm_b, 512, 128, VOCAB);
}

// Round 7
// 4068.600 us; speedup vs baseline: 1.1089x; 1.1089x over previous
//
#include <hip/hip_runtime.h>
#include <hip/hip_bf16.h>
#include <math.h>

// Problem constants
#define NTOK  65536      // B*T
#define CDIM  512
#define NHEAD 8
#define HSZ   64
#define NLAYER 6
#define DFF   2048
#define VOCAB 65

typedef unsigned short u16;
typedef __attribute__((ext_vector_type(8))) __bf16 bf16x8;
typedef __attribute__((ext_vector_type(4))) float f32x4;
typedef __attribute__((ext_vector_type(8))) unsigned short ushort8;

__device__ __forceinline__ float b2f(u16 u) {
    union { unsigned int i; float f; } x; x.i = ((unsigned int)u) << 16; return x.f;
}
__device__ __forceinline__ u16 f2b(float f) {
    union { float f; unsigned int i; } x; x.f = f;
    unsigned int r = x.i + 0x7fffu + ((x.i >> 16) & 1u);   // RNE
    return (u16)(r >> 16);
}

__device__ __forceinline__ void async16(const u16* g, u16* l) {
    __builtin_amdgcn_global_load_lds(
        (const __attribute__((address_space(1))) void*)g,
        (__attribute__((address_space(3))) void*)l, 16, 0, 0);
}

// ---------------------------------------------------------------------------
// GEMM: C[M x N] = A[M x K] @ Bt[N x K]^T   (A,Bt bf16; fp32 MFMA accum)
// EPI: 0 plain->bf16, 1 +bias+res->bf16 (res may alias Cout: in-place),
//      2 relu(+bias)->bf16, 3 +bias->f32 masked col<Nout
// R4's measured-best structure (31% MfmaUtil, 3 blocks/CU): 256x128 tile,
// 512 thr (8 waves, 64x64 each), BK=64 two-barrier K-loop. R5 (single-barrier
// dbuf) and R6 (84KB-LDS LN fusion, 1 block/CU) both regressed — keep this.
// Swapped-operand MFMA: lane holds 4 consecutive N-cols -> 8B vector stores.
// XCD swizzle: id%8 = XCD owns whole m-stripes. Requires gridDim.y % 8 == 0.
// ---------------------------------------------------------------------------
template<int EPI>
__global__ __launch_bounds__(512)
void gemm_bt(const u16* __restrict__ A, const u16* __restrict__ Bt,
             void* __restrict__ Cout, const float* __restrict__ bias,
             const u16* __restrict__ res, int K, int N, int Nout)
{
    __shared__ u16 lA[2 * 256 * 32];   // [panel][row<256][32]  32 KB
    __shared__ u16 lB[2 * 128 * 32];   // [panel][row<128][32]  16 KB
    const int tid  = threadIdx.x;

    // XCD-aware swizzle
    const int Nx = gridDim.x;
    const int id = blockIdx.y * Nx + blockIdx.x;
    const int xcd = id & 7;
    const int j0  = id >> 3;
    const int mt  = xcd + 8 * (j0 / Nx);
    const int nt  = j0 - (j0 / Nx) * Nx;
    const int m0  = mt * 256;
    const int n0  = nt * 128;

    const int lane = tid & 63;
    const int wv   = tid >> 6;         // 0..7
    const int wr   = (wv >> 1) * 64;   // wave row offset (0,64,128,192)
    const int wc   = (wv & 1) * 64;    // wave col offset (0,64)
    const int r16  = lane & 15;
    const int quad = lane >> 4;

    f32x4 acc[4][4] = {};              // acc[j][i], swapped-operand layout

    const int srow = tid >> 2, skseg = (tid & 3) * 8;
    const u16* pA  = A  + (size_t)(m0 + srow) * K + skseg;   // rows 0..127
    const u16* pA2 = pA + (size_t)128 * K;                   // rows 128..255
    const u16* pB  = Bt + (size_t)(n0 + srow) * K + skseg;
    u16* lAt = &lA[(size_t)tid * 8];
    u16* lBt = &lB[(size_t)tid * 8];

    for (int k0 = 0; k0 < K; k0 += 64) {
        async16(pA  + k0,      lAt);            // panel0 rows 0..127
        async16(pA2 + k0,      lAt + 4096);     // panel0 rows 128..255
        async16(pA  + k0 + 32, lAt + 8192);     // panel1 rows 0..127
        async16(pA2 + k0 + 32, lAt + 12288);    // panel1 rows 128..255
        async16(pB  + k0,      lBt);            // panel0
        async16(pB  + k0 + 32, lBt + 4096);     // panel1
        __syncthreads();   // drains vmcnt -> LDS valid

#pragma unroll
        for (int s = 0; s < 2; s++) {
            const u16* bA = &lA[s * 8192];
            const u16* bB = &lB[s * 4096];
            bf16x8 af[4], bfr[4];
#pragma unroll
            for (int i = 0; i < 4; i++)
                af[i] = *(const bf16x8*)(const void*)&bA[(wr + i * 16 + r16) * 32 + quad * 8];
#pragma unroll
            for (int j = 0; j < 4; j++)
                bfr[j] = *(const bf16x8*)(const void*)&bB[(wc + j * 16 + r16) * 32 + quad * 8];
#pragma unroll
            for (int j = 0; j < 4; j++)
#pragma unroll
                for (int i = 0; i < 4; i++)
                    acc[j][i] = __builtin_amdgcn_mfma_f32_16x16x32_bf16(bfr[j], af[i], acc[j][i], 0, 0, 0);
        }
        __syncthreads();   // all reads done before next stage overwrites
    }

    // epilogue (swapped layout): row = wr+i*16+r16, cols = wc+j*16+quad*4+r
#pragma unroll
    for (int i = 0; i < 4; i++) {
        const int row = m0 + wr + i * 16 + r16;
#pragma unroll
        for (int j = 0; j < 4; j++) {
            const int colb = n0 + wc + j * 16 + quad * 4;
            float v[4];
#pragma unroll
            for (int r = 0; r < 4; r++) v[r] = acc[j][i][r];
            if (EPI == 1 || EPI == 2) {
                const f32x4 b4 = *(const f32x4*)(const void*)&bias[colb];
#pragma unroll
                for (int r = 0; r < 4; r++) v[r] += b4[r];
            }
            if (EPI == 1) {
                const uint2 rv = *(const uint2*)(const void*)&res[(size_t)row * N + colb];
                v[0] += b2f((u16)(rv.x & 0xffffu));
                v[1] += b2f((u16)(rv.x >> 16));
                v[2] += b2f((u16)(rv.y & 0xffffu));
                v[3] += b2f((u16)(rv.y >> 16));
            }
            if (EPI == 2) {
#pragma unroll
                for (int r = 0; r < 4; r++) v[r] = fmaxf(v[r], 0.f);
            }
            if (EPI == 3) {
#pragma unroll
                for (int r = 0; r < 4; r++) {
                    const int col = colb + r;
                    if (col < Nout)
                        ((float*)Cout)[(size_t)row * Nout + col] = v[r] + bias[col];
                }
            } else {
                uint2 o;
                o.x = (unsigned)f2b(v[0]) | ((unsigned)f2b(v[1]) << 16);
                o.y = (unsigned)f2b(v[2]) | ((unsigned)f2b(v[3]) << 16);
                *(uint2*)(void*)&((u16*)Cout)[(size_t)row * N + colb] = o;
            }
        }
    }
}

// ---------------------------------------------------------------------------
// Attention: one wave per (b,h). T=8, HS=64. qkv layout [token][q|k|v, h*64+d].
// Vectorized: ushort8 global loads (3/lane vs 24 scalar); LDS rows padded to
// 65 floats (R2-R6 stride-64 gave 8-way bank conflicts in the score loop);
// PV phase: lane=(tt,d0) computes 8 dims -> one b128 store.
// NOTE: reference scale = C^-0.5 = 512^-0.5 (not HS^-0.5).
// ---------------------------------------------------------------------------
__global__ __launch_bounds__(256)
void attn_k(const u16* __restrict__ qkv, u16* __restrict__ out)
{
    __shared__ float sq[4][8][65], sk[4][8][65], sv[4][8][65], sp[4][64];
    const int w = threadIdx.x >> 6, lane = threadIdx.x & 63;
    const int unit = blockIdx.x * 4 + w;        // local b*8 + h
    const int b = unit >> 3, h = unit & 7;
    const size_t base = (size_t)b * 8 * 1536 + h * 64;
    {
        const int t = lane >> 3, d0 = (lane & 7) * 8;
        const ushort8 q8 = *(const ushort8*)(const void*)&qkv[base + t * 1536 + d0];
        const ushort8 k8 = *(const ushort8*)(const void*)&qkv[base + t * 1536 + 512 + d0];
        const ushort8 v8 = *(const ushort8*)(const void*)&qkv[base + t * 1536 + 1024 + d0];
#pragma unroll
        for (int i = 0; i < 8; i++) {
            sq[w][t][d0 + i] = b2f(q8[i]);
            sk[w][t][d0 + i] = b2f(k8[i]);
            sv[w][t][d0 + i] = b2f(v8[i]);
        }
    }
    __syncthreads();
    const int t = lane >> 3, s = lane & 7;
    float sc = -1e30f;
    if (s <= t) {
        float d = 0.f;
#pragma unroll
        for (int c = 0; c < 64; c++) d += sq[w][t][c] * sk[w][s][c];
        sc = d * 0.04419417382415922f;          // 512^-0.5
    }
    float mx = sc;
#pragma unroll
    for (int m = 1; m < 8; m <<= 1) mx = fmaxf(mx, __shfl_xor(mx, m, 8));
    float e = __expf(sc - mx);
    if (s > t) e = 0.f;
    float sum = e;
#pragma unroll
    for (int m = 1; m < 8; m <<= 1) sum += __shfl_xor(sum, m, 8);
    sp[w][lane] = e / sum;
    __syncthreads();
    {
        const int tt = lane >> 3, d0 = (lane & 7) * 8;
        float a[8] = {};
#pragma unroll
        for (int ss = 0; ss < 8; ss++) {
            const float p = sp[w][tt * 8 + ss];
#pragma unroll
            for (int i = 0; i < 8; i++) a[i] += p * sv[w][ss][d0 + i];
        }
        ushort8 o;
#pragma unroll
        for (int i = 0; i < 8; i++) o[i] = f2b(a[i]);
        *(ushort8*)(void*)&out[((size_t)b * 8 + tt) * 512 + h * 64 + d0] = o;
    }
}

// ---------------------------------------------------------------------------
// LayerNorm: wave per token, 8 elems/lane, shuffle reduction. In-place OK.
// ---------------------------------------------------------------------------
__global__ __launch_bounds__(256)
void ln_k(const u16* __restrict__ y, const float* __restrict__ g,
          const float* __restrict__ be, u16* __restrict__ x)
{
    const int w = threadIdx.x >> 6, lane = threadIdx.x & 63;
    const size_t tok = (size_t)blockIdx.x * 4 + w;
    const u16* row = y + tok * 512 + lane * 8;
    ushort8 raw = *(const ushort8*)(const void*)row;
    float v[8];
#pragma unroll
    for (int i = 0; i < 8; i++) v[i] = b2f(raw[i]);
    float s = 0.f;
#pragma unroll
    for (int i = 0; i < 8; i++) s += v[i];
#pragma unroll
    for (int m = 1; m < 64; m <<= 1) s += __shfl_xor(s, m, 64);
    const float mu = s * (1.f / 512.f);
    float q = 0.f;
#pragma unroll
    for (int i = 0; i < 8; i++) { float d = v[i] - mu; q += d * d; }
#pragma unroll
    for (int m = 1; m < 64; m <<= 1) q += __shfl_xor(q, m, 64);
    const float inv = rsqrtf(q * (1.f / 512.f) + 1e-5f);
    f32x4 g0  = *(const f32x4*)(const void*)&g[lane * 8];
    f32x4 g1  = *(const f32x4*)(const void*)&g[lane * 8 + 4];
    f32x4 b0  = *(const f32x4*)(const void*)&be[lane * 8];
    f32x4 b1v = *(const f32x4*)(const void*)&be[lane * 8 + 4];
    ushort8 o;
#pragma unroll
    for (int i = 0; i < 4; i++) o[i]     = f2b((v[i] - mu) * inv * g0[i] + b0[i]);
#pragma unroll
    for (int i = 0; i < 4; i++) o[i + 4] = f2b((v[i + 4] - mu) * inv * g1[i] + b1v[i]);
    *(ushort8*)(void*)&x[tok * 512 + lane * 8] = o;
}

// ---------------------------------------------------------------------------
// Embedding: vectorized. thread -> (token, 8-col segment).
// ---------------------------------------------------------------------------
__global__ __launch_bounds__(256)
void embed_k(const int* __restrict__ idx, const float* __restrict__ tokt,
             const float* __restrict__ pos, u16* __restrict__ xb)
{
    const int gid = blockIdx.x * 256 + threadIdx.x;    // < NTOK*64
    const int tk = gid >> 6, seg = (gid & 63) * 8;
    const int t = tk & 7;
    const int ix = idx[tk];
    const f32x4 a0 = *(const f32x4*)(const void*)&tokt[(size_t)ix * 512 + seg];
    const f32x4 a1 = *(const f32x4*)(const void*)&tokt[(size_t)ix * 512 + seg + 4];
    const f32x4 p0 = *(const f32x4*)(const void*)&pos[t * 512 + seg];
    const f32x4 p1 = *(const f32x4*)(const void*)&pos[t * 512 + seg + 4];
    ushort8 o;
#pragma unroll
    for (int i = 0; i < 4; i++) o[i]     = f2b(a0[i] + p0[i]);
#pragma unroll
    for (int i = 0; i < 4; i++) o[i + 4] = f2b(a1[i] + p1[i]);
    *(ushort8*)(void*)&xb[(size_t)tk * 512 + seg] = o;
}

// ---------------------------------------------------------------------------
// Weight converts (fp32 -> bf16 B^T layouts), LDS-tiled transposes
// ---------------------------------------------------------------------------
__global__ __launch_bounds__(256)
void conv_t2_k(const float* __restrict__ in, u16* __restrict__ out, int K, int N)
{
    __shared__ float t[32][33];
    const int tx = threadIdx.x & 31, ty4 = (threadIdx.x >> 5) * 4;
    const int n0 = blockIdx.x * 32, k0 = blockIdx.y * 32, l = blockIdx.z;
    const size_t per = (size_t)K * N;
    const float* src = in + l * per;
#pragma unroll
    for (int r = 0; r < 4; r++)
        t[ty4 + r][tx] = src[(size_t)(k0 + ty4 + r) * N + n0 + tx];
    __syncthreads();
    u16* dst = out + l * per;
#pragma unroll
    for (int r = 0; r < 4; r++)
        dst[(size_t)(n0 + ty4 + r) * K + k0 + tx] = f2b(t[tx][ty4 + r]);
}

__global__ __launch_bounds__(256)
void conv_qkv2_k(const float* __restrict__ wq, const float* __restrict__ wk,
                 const float* __restrict__ wv, u16* __restrict__ out)
{
    __shared__ float t[32][33];
    const int tx = threadIdx.x & 31, ty4 = (threadIdx.x >> 5) * 4;
    const int c0 = blockIdx.x * 32, d0 = blockIdx.y * 32;
    const int z = blockIdx.z;
    const int sel = z / 48, rem = z - sel * 48;
    const int l = rem >> 3, h = rem & 7;
    const float* src = (sel == 0) ? wq : (sel == 1) ? wk : wv;
    const float* sb = src + (((size_t)l * 8 + h) * 512) * 64;
#pragma unroll
    for (int r = 0; r < 4; r++)
        t[ty4 + r][tx] = sb[(size_t)(c0 + ty4 + r) * 64 + d0 + tx];
    __syncthreads();
    u16* dst = out + (size_t)l * 786432 + (size_t)(sel * 512 + h * 64 + d0) * 512;
#pragma unroll
    for (int r = 0; r < 4; r++)
        dst[(size_t)(ty4 + r) * 512 + c0 + tx] = f2b(t[tx][ty4 + r]);
}

__global__ __launch_bounds__(256)
void conv_lm_k(const float* __restrict__ lm_w, u16* __restrict__ out)
{
    int gid = blockIdx.x * 256 + threadIdx.x;        // < 128*512
    int n = gid >> 9, c = gid & 511;
    out[gid] = (n < VOCAB) ? f2b(lm_w[(size_t)c * VOCAB + n]) : (u16)0;
}

// ---------------------------------------------------------------------------
extern "C" void kernel_launch(void* const* d_in, const int* in_sizes, int n_in,
                              void* d_out, int out_size, void* d_ws, size_t ws_size,
                              hipStream_t stream)
{
    const int*   idx    = (const int*)  d_in[0];
    const float* tokt   = (const float*)d_in[1];
    const float* post   = (const float*)d_in[2];
    const float* wq     = (const float*)d_in[3];
    const float* wk     = (const float*)d_in[4];
    const float* wvp    = (const float*)d_in[5];
    const float* proj_w = (const float*)d_in[6];
    const float* proj_b = (const float*)d_in[7];
    const float* w1     = (const float*)d_in[8];
    const float* b1     = (const float*)d_in[9];
    const float* w2     = (const float*)d_in[10];
    const float* b2     = (const float*)d_in[11];
    const float* ln1_g  = (const float*)d_in[12];
    const float* ln1_b  = (const float*)d_in[13];
    const float* ln2_g  = (const float*)d_in[14];
    const float* ln2_b  = (const float*)d_in[15];
    const float* lm_w   = (const float*)d_in[16];
    const float* lm_b   = (const float*)d_in[17];
    float* out = (float*)d_out;

    char* ws = (char*)d_ws;
    u16* wqkvt = (u16*)(ws + 0);                     //  9,437,184
    u16* wprjt = (u16*)(ws + 9437184);               //  3,145,728
    u16* ww1t  = (u16*)(ws + 12582912);              // 12,582,912
    u16* ww2t  = (u16*)(ws + 25165824);              // 12,582,912
    u16* wlmt  = (u16*)(ws + 37748736);              //    131,072
    u16* xb    = (u16*)(ws + 37879808);              // 67,108,864  residual
    char* big  = ws + 104988672;                     // chunk*4096 transient

    const size_t fixed_bytes = 104988672ull;
    int chunk = 4096;
    const int cands[4] = {65536, 32768, 16384, 8192};
    for (int i = 0; i < 4; i++) {
        if (fixed_bytes + (size_t)cands[i] * 4096ull <= ws_size) { chunk = cands[i]; break; }
    }
    const int nchunks = NTOK / chunk;
    u16* qkvc  = (u16*)big;                          // chunk x 1536
    u16* attnc = (u16*)(big + (size_t)chunk * 3072); // chunk x 512
    u16* h1c   = (u16*)big;                          // chunk x 2048

    conv_qkv2_k<<<dim3(16, 2, 144), 256, 0, stream>>>(wq, wk, wvp, wqkvt);
    conv_t2_k  <<<dim3(16, 16, 6), 256, 0, stream>>>(proj_w, wprjt, 512, 512);
    conv_t2_k  <<<dim3(64, 16, 6), 256, 0, stream>>>(w1, ww1t, 512, 2048);
    conv_t2_k  <<<dim3(16, 64, 6), 256, 0, stream>>>(w2, ww2t, 2048, 512);
    conv_lm_k  <<<128 * 512 / 256, 256, 0, stream>>>(lm_w, wlmt);

    embed_k<<<NTOK * 64 / 256, 256, 0, stream>>>(idx, tokt, post, xb);

    for (int l = 0; l < NLAYER; l++) {
        // ---- attention phase, chunked over tokens ----
        for (int c = 0; c < nchunks; c++) {
            const size_t t0 = (size_t)c * chunk;
            // qkv = x @ Wqkv
            gemm_bt<0><<<dim3(12, chunk / 256), 512, 0, stream>>>(
                xb + t0 * 512, wqkvt + (size_t)l * 786432, qkvc,
                nullptr, nullptr, 512, 1536, 1536);
            // attention (chunk-local)
            attn_k<<<chunk / 4, 256, 0, stream>>>(qkvc, attnc);
            // x = attno @ proj_w + proj_b + x   (in-place residual)
            gemm_bt<1><<<dim3(4, chunk / 256), 512, 0, stream>>>(
                attnc, wprjt + (size_t)l * 262144, xb + t0 * 512,
                proj_b + l * 512, xb + t0 * 512, 512, 512, 512);
        }
        // x = LN1(x)  (in-place)
        ln_k<<<NTOK / 4, 256, 0, stream>>>(xb, ln1_g + l * 512, ln1_b + l * 512, xb);
        // ---- MLP phase, chunked over tokens ----
        for (int c = 0; c < nchunks; c++) {
            const size_t t0 = (size_t)c * chunk;
            // h1 = relu(x @ w1 + b1)
            gemm_bt<2><<<dim3(16, chunk / 256), 512, 0, stream>>>(
                xb + t0 * 512, ww1t + (size_t)l * 1048576, h1c,
                b1 + l * 2048, nullptr, 512, 2048, 2048);
            // x = h1 @ w2 + b2 + x   (in-place residual)
            gemm_bt<1><<<dim3(4, chunk / 256), 512, 0, stream>>>(
                h1c, ww2t + (size_t)l * 1048576, xb + t0 * 512,
                b2 + l * 512, xb + t0 * 512, 2048, 512, 512);
        }
        // x = LN2(x)  (in-place)
        ln_k<<<NTOK / 4, 256, 0, stream>>>(xb, ln2_g + l * 512, ln2_b + l * 512, xb);
    }

    // logits = x @ lm_w + lm_b  (N padded to 128, masked fp32 store)
    gemm_bt<3><<<dim3(1, 256), 512, 0, stream>>>(
        xb, wlmt, out, lm_b, nullptr, 512, 128, VOCAB);
}

// Round 8
// 3928.676 us; speedup vs baseline: 1.1484x; 1.0356x over previous
//
#include <hip/hip_runtime.h>
#include <hip/hip_bf16.h>
#include <math.h>

// Problem constants
#define NTOK  65536      // B*T
#define CDIM  512
#define NHEAD 8
#define HSZ   64
#define NLAYER 6
#define DFF   2048
#define VOCAB 65

typedef unsigned short u16;
typedef __attribute__((ext_vector_type(8))) __bf16 bf16x8;
typedef __attribute__((ext_vector_type(4))) float f32x4;
typedef __attribute__((ext_vector_type(8))) unsigned short ushort8;

__device__ __forceinline__ float b2f(u16 u) {
    union { unsigned int i; float f; } x; x.i = ((unsigned int)u) << 16; return x.f;
}
__device__ __forceinline__ u16 f2b(float f) {
    union { float f; unsigned int i; } x; x.f = f;
    unsigned int r = x.i + 0x7fffu + ((x.i >> 16) & 1u);   // RNE
    return (u16)(r >> 16);
}

__device__ __forceinline__ void async16(const u16* g, u16* l) {
    __builtin_amdgcn_global_load_lds(
        (const __attribute__((address_space(1))) void*)g,
        (__attribute__((address_space(3))) void*)l, 16, 0, 0);
}

// ---------------------------------------------------------------------------
// GEMM: C[M x N] = A[M x K] @ Bt[N x K]^T   (A,Bt bf16; fp32 MFMA accum)
// A row stride = lda (elements) — lets proj read the q-slot of qkvc (1536).
// EPI: 0 plain->bf16, 1 +bias+res->bf16 (res may alias Cout: in-place),
//      2 relu(+bias)->bf16, 3 +bias->f32 masked col<Nout
// Measured-best structure (R4/R7, ~28-31% MfmaUtil, 3 blocks/CU): 256x128
// tile, 512 thr (8 waves, 64x64 each), BK=64 two-barrier K-loop. R5's
// single-barrier dbuf and R6's 84KB LN fusion both regressed — do not touch.
// Swapped-operand MFMA: lane holds 4 consecutive N-cols -> 8B vector stores
// (WRITE_SIZE exactly = tensor size, no write-allocate overhead).
// XCD swizzle: id%8 = XCD owns whole m-stripes. Requires gridDim.y % 8 == 0.
// ---------------------------------------------------------------------------
template<int EPI>
__global__ __launch_bounds__(512)
void gemm_bt(const u16* __restrict__ A, const u16* __restrict__ Bt,
             void* __restrict__ Cout, const float* __restrict__ bias,
             const u16* __restrict__ res, int K, int lda, int N, int Nout)
{
    __shared__ u16 lA[2 * 256 * 32];   // [panel][row<256][32]  32 KB
    __shared__ u16 lB[2 * 128 * 32];   // [panel][row<128][32]  16 KB
    const int tid  = threadIdx.x;

    // XCD-aware swizzle
    const int Nx = gridDim.x;
    const int id = blockIdx.y * Nx + blockIdx.x;
    const int xcd = id & 7;
    const int j0  = id >> 3;
    const int mt  = xcd + 8 * (j0 / Nx);
    const int nt  = j0 - (j0 / Nx) * Nx;
    const int m0  = mt * 256;
    const int n0  = nt * 128;

    const int lane = tid & 63;
    const int wv   = tid >> 6;         // 0..7
    const int wr   = (wv >> 1) * 64;   // wave row offset (0,64,128,192)
    const int wc   = (wv & 1) * 64;    // wave col offset (0,64)
    const int r16  = lane & 15;
    const int quad = lane >> 4;

    f32x4 acc[4][4] = {};              // acc[j][i], swapped-operand layout

    const int srow = tid >> 2, skseg = (tid & 3) * 8;
    const u16* pA  = A  + (size_t)(m0 + srow) * lda + skseg;  // rows 0..127
    const u16* pA2 = pA + (size_t)128 * lda;                  // rows 128..255
    const u16* pB  = Bt + (size_t)(n0 + srow) * K + skseg;
    u16* lAt = &lA[(size_t)tid * 8];
    u16* lBt = &lB[(size_t)tid * 8];

    for (int k0 = 0; k0 < K; k0 += 64) {
        async16(pA  + k0,      lAt);            // panel0 rows 0..127
        async16(pA2 + k0,      lAt + 4096);     // panel0 rows 128..255
        async16(pA  + k0 + 32, lAt + 8192);     // panel1 rows 0..127
        async16(pA2 + k0 + 32, lAt + 12288);    // panel1 rows 128..255
        async16(pB  + k0,      lBt);            // panel0
        async16(pB  + k0 + 32, lBt + 4096);     // panel1
        __syncthreads();   // drains vmcnt -> LDS valid

#pragma unroll
        for (int s = 0; s < 2; s++) {
            const u16* bA = &lA[s * 8192];
            const u16* bB = &lB[s * 4096];
            bf16x8 af[4], bfr[4];
#pragma unroll
            for (int i = 0; i < 4; i++)
                af[i] = *(const bf16x8*)(const void*)&bA[(wr + i * 16 + r16) * 32 + quad * 8];
#pragma unroll
            for (int j = 0; j < 4; j++)
                bfr[j] = *(const bf16x8*)(const void*)&bB[(wc + j * 16 + r16) * 32 + quad * 8];
#pragma unroll
            for (int j = 0; j < 4; j++)
#pragma unroll
                for (int i = 0; i < 4; i++)
                    acc[j][i] = __builtin_amdgcn_mfma_f32_16x16x32_bf16(bfr[j], af[i], acc[j][i], 0, 0, 0);
        }
        __syncthreads();   // all reads done before next stage overwrites
    }

    // epilogue (swapped layout): row = wr+i*16+r16, cols = wc+j*16+quad*4+r
#pragma unroll
    for (int i = 0; i < 4; i++) {
        const int row = m0 + wr + i * 16 + r16;
#pragma unroll
        for (int j = 0; j < 4; j++) {
            const int colb = n0 + wc + j * 16 + quad * 4;
            float v[4];
#pragma unroll
            for (int r = 0; r < 4; r++) v[r] = acc[j][i][r];
            if (EPI == 1 || EPI == 2) {
                const f32x4 b4 = *(const f32x4*)(const void*)&bias[colb];
#pragma unroll
                for (int r = 0; r < 4; r++) v[r] += b4[r];
            }
            if (EPI == 1) {
                const uint2 rv = *(const uint2*)(const void*)&res[(size_t)row * N + colb];
                v[0] += b2f((u16)(rv.x & 0xffffu));
                v[1] += b2f((u16)(rv.x >> 16));
                v[2] += b2f((u16)(rv.y & 0xffffu));
                v[3] += b2f((u16)(rv.y >> 16));
            }
            if (EPI == 2) {
#pragma unroll
                for (int r = 0; r < 4; r++) v[r] = fmaxf(v[r], 0.f);
            }
            if (EPI == 3) {
#pragma unroll
                for (int r = 0; r < 4; r++) {
                    const int col = colb + r;
                    if (col < Nout)
                        ((float*)Cout)[(size_t)row * Nout + col] = v[r] + bias[col];
                }
            } else {
                uint2 o;
                o.x = (unsigned)f2b(v[0]) | ((unsigned)f2b(v[1]) << 16);
                o.y = (unsigned)f2b(v[2]) | ((unsigned)f2b(v[3]) << 16);
                *(uint2*)(void*)&((u16*)Cout)[(size_t)row * N + colb] = o;
            }
        }
    }
}

// ---------------------------------------------------------------------------
// Attention: one wave per (b,h). T=8, HS=64. qkv layout [token][q|k|v, h*64+d].
// IN-PLACE: output written into the q-slot (each wave exclusively owns its
// (b,h) q-slice; q fully consumed into LDS before the store). Vectorized
// ushort8 loads/stores; LDS rows padded to 65 (kills 8-way bank conflicts).
// NOTE: reference scale = C^-0.5 = 512^-0.5 (not HS^-0.5).
// ---------------------------------------------------------------------------
__global__ __launch_bounds__(256)
void attn_k(u16* __restrict__ qkv)
{
    __shared__ float sq[4][8][65], sk[4][8][65], sv[4][8][65], sp[4][64];
    const int w = threadIdx.x >> 6, lane = threadIdx.x & 63;
    const int unit = blockIdx.x * 4 + w;        // local b*8 + h
    const int b = unit >> 3, h = unit & 7;
    const size_t base = (size_t)b * 8 * 1536 + h * 64;
    {
        const int t = lane >> 3, d0 = (lane & 7) * 8;
        const ushort8 q8 = *(const ushort8*)(const void*)&qkv[base + t * 1536 + d0];
        const ushort8 k8 = *(const ushort8*)(const void*)&qkv[base + t * 1536 + 512 + d0];
        const ushort8 v8 = *(const ushort8*)(const void*)&qkv[base + t * 1536 + 1024 + d0];
#pragma unroll
        for (int i = 0; i < 8; i++) {
            sq[w][t][d0 + i] = b2f(q8[i]);
            sk[w][t][d0 + i] = b2f(k8[i]);
            sv[w][t][d0 + i] = b2f(v8[i]);
        }
    }
    __syncthreads();
    const int t = lane >> 3, s = lane & 7;
    float sc = -1e30f;
    if (s <= t) {
        float d = 0.f;
#pragma unroll
        for (int c = 0; c < 64; c++) d += sq[w][t][c] * sk[w][s][c];
        sc = d * 0.04419417382415922f;          // 512^-0.5
    }
    float mx = sc;
#pragma unroll
    for (int m = 1; m < 8; m <<= 1) mx = fmaxf(mx, __shfl_xor(mx, m, 8));
    float e = __expf(sc - mx);
    if (s > t) e = 0.f;
    float sum = e;
#pragma unroll
    for (int m = 1; m < 8; m <<= 1) sum += __shfl_xor(sum, m, 8);
    sp[w][lane] = e / sum;
    __syncthreads();
    {
        const int tt = lane >> 3, d0 = (lane & 7) * 8;
        float a[8] = {};
#pragma unroll
        for (int ss = 0; ss < 8; ss++) {
            const float p = sp[w][tt * 8 + ss];
#pragma unroll
            for (int i = 0; i < 8; i++) a[i] += p * sv[w][ss][d0 + i];
        }
        ushort8 o;
#pragma unroll
        for (int i = 0; i < 8; i++) o[i] = f2b(a[i]);
        *(ushort8*)(void*)&qkv[base + tt * 1536 + d0] = o;   // q-slot
    }
}

// ---------------------------------------------------------------------------
// LayerNorm: wave per token, 8 elems/lane, shuffle reduction. In-place OK.
// ---------------------------------------------------------------------------
__global__ __launch_bounds__(256)
void ln_k(const u16* __restrict__ y, const float* __restrict__ g,
          const float* __restrict__ be, u16* __restrict__ x)
{
    const int w = threadIdx.x >> 6, lane = threadIdx.x & 63;
    const size_t tok = (size_t)blockIdx.x * 4 + w;
    const u16* row = y + tok * 512 + lane * 8;
    ushort8 raw = *(const ushort8*)(const void*)row;
    float v[8];
#pragma unroll
    for (int i = 0; i < 8; i++) v[i] = b2f(raw[i]);
    float s = 0.f;
#pragma unroll
    for (int i = 0; i < 8; i++) s += v[i];
#pragma unroll
    for (int m = 1; m < 64; m <<= 1) s += __shfl_xor(s, m, 64);
    const float mu = s * (1.f / 512.f);
    float q = 0.f;
#pragma unroll
    for (int i = 0; i < 8; i++) { float d = v[i] - mu; q += d * d; }
#pragma unroll
    for (int m = 1; m < 64; m <<= 1) q += __shfl_xor(q, m, 64);
    const float inv = rsqrtf(q * (1.f / 512.f) + 1e-5f);
    f32x4 g0  = *(const f32x4*)(const void*)&g[lane * 8];
    f32x4 g1  = *(const f32x4*)(const void*)&g[lane * 8 + 4];
    f32x4 b0  = *(const f32x4*)(const void*)&be[lane * 8];
    f32x4 b1v = *(const f32x4*)(const void*)&be[lane * 8 + 4];
    ushort8 o;
#pragma unroll
    for (int i = 0; i < 4; i++) o[i]     = f2b((v[i] - mu) * inv * g0[i] + b0[i]);
#pragma unroll
    for (int i = 0; i < 4; i++) o[i + 4] = f2b((v[i + 4] - mu) * inv * g1[i] + b1v[i]);
    *(ushort8*)(void*)&x[tok * 512 + lane * 8] = o;
}

// ---------------------------------------------------------------------------
// Embedding: vectorized. thread -> (token, 8-col segment).
// ---------------------------------------------------------------------------
__global__ __launch_bounds__(256)
void embed_k(const int* __restrict__ idx, const float* __restrict__ tokt,
             const float* __restrict__ pos, u16* __restrict__ xb)
{
    const int gid = blockIdx.x * 256 + threadIdx.x;    // < NTOK*64
    const int tk = gid >> 6, seg = (gid & 63) * 8;
    const int t = tk & 7;
    const int ix = idx[tk];
    const f32x4 a0 = *(const f32x4*)(const void*)&tokt[(size_t)ix * 512 + seg];
    const f32x4 a1 = *(const f32x4*)(const void*)&tokt[(size_t)ix * 512 + seg + 4];
    const f32x4 p0 = *(const f32x4*)(const void*)&pos[t * 512 + seg];
    const f32x4 p1 = *(const f32x4*)(const void*)&pos[t * 512 + seg + 4];
    ushort8 o;
#pragma unroll
    for (int i = 0; i < 4; i++) o[i]     = f2b(a0[i] + p0[i]);
#pragma unroll
    for (int i = 0; i < 4; i++) o[i + 4] = f2b(a1[i] + p1[i]);
    *(ushort8*)(void*)&xb[(size_t)tk * 512 + seg] = o;
}

// ---------------------------------------------------------------------------
// Weight converts (fp32 -> bf16 B^T layouts), LDS-tiled transposes
// ---------------------------------------------------------------------------
__global__ __launch_bounds__(256)
void conv_t2_k(const float* __restrict__ in, u16* __restrict__ out, int K, int N)
{
    __shared__ float t[32][33];
    const int tx = threadIdx.x & 31, ty4 = (threadIdx.x >> 5) * 4;
    const int n0 = blockIdx.x * 32, k0 = blockIdx.y * 32, l = blockIdx.z;
    const size_t per = (size_t)K * N;
    const float* src = in + l * per;
#pragma unroll
    for (int r = 0; r < 4; r++)
        t[ty4 + r][tx] = src[(size_t)(k0 + ty4 + r) * N + n0 + tx];
    __syncthreads();
    u16* dst = out + l * per;
#pragma unroll
    for (int r = 0; r < 4; r++)
        dst[(size_t)(n0 + ty4 + r) * K + k0 + tx] = f2b(t[tx][ty4 + r]);
}

__global__ __launch_bounds__(256)
void conv_qkv2_k(const float* __restrict__ wq, const float* __restrict__ wk,
                 const float* __restrict__ wv, u16* __restrict__ out)
{
    __shared__ float t[32][33];
    const int tx = threadIdx.x & 31, ty4 = (threadIdx.x >> 5) * 4;
    const int c0 = blockIdx.x * 32, d0 = blockIdx.y * 32;
    const int z = blockIdx.z;
    const int sel = z / 48, rem = z - sel * 48;
    const int l = rem >> 3, h = rem & 7;
    const float* src = (sel == 0) ? wq : (sel == 1) ? wk : wv;
    const float* sb = src + (((size_t)l * 8 + h) * 512) * 64;
#pragma unroll
    for (int r = 0; r < 4; r++)
        t[ty4 + r][tx] = sb[(size_t)(c0 + ty4 + r) * 64 + d0 + tx];
    __syncthreads();
    u16* dst = out + (size_t)l * 786432 + (size_t)(sel * 512 + h * 64 + d0) * 512;
#pragma unroll
    for (int r = 0; r < 4; r++)
        dst[(size_t)(ty4 + r) * 512 + c0 + tx] = f2b(t[tx][ty4 + r]);
}

__global__ __launch_bounds__(256)
void conv_lm_k(const float* __restrict__ lm_w, u16* __restrict__ out)
{
    int gid = blockIdx.x * 256 + threadIdx.x;        // < 128*512
    int n = gid >> 9, c = gid & 511;
    out[gid] = (n < VOCAB) ? f2b(lm_w[(size_t)c * VOCAB + n]) : (u16)0;
}

// ---------------------------------------------------------------------------
extern "C" void kernel_launch(void* const* d_in, const int* in_sizes, int n_in,
                              void* d_out, int out_size, void* d_ws, size_t ws_size,
                              hipStream_t stream)
{
    const int*   idx    = (const int*)  d_in[0];
    const float* tokt   = (const float*)d_in[1];
    const float* post   = (const float*)d_in[2];
    const float* wq     = (const float*)d_in[3];
    const float* wk     = (const float*)d_in[4];
    const float* wvp    = (const float*)d_in[5];
    const float* proj_w = (const float*)d_in[6];
    const float* proj_b = (const float*)d_in[7];
    const float* w1     = (const float*)d_in[8];
    const float* b1     = (const float*)d_in[9];
    const float* w2     = (const float*)d_in[10];
    const float* b2     = (const float*)d_in[11];
    const float* ln1_g  = (const float*)d_in[12];
    const float* ln1_b  = (const float*)d_in[13];
    const float* ln2_g  = (const float*)d_in[14];
    const float* ln2_b  = (const float*)d_in[15];
    const float* lm_w   = (const float*)d_in[16];
    const float* lm_b   = (const float*)d_in[17];
    float* out = (float*)d_out;

    char* ws = (char*)d_ws;
    u16* wqkvt = (u16*)(ws + 0);                     //  9,437,184
    u16* wprjt = (u16*)(ws + 9437184);               //  3,145,728
    u16* ww1t  = (u16*)(ws + 12582912);              // 12,582,912
    u16* ww2t  = (u16*)(ws + 25165824);              // 12,582,912
    u16* wlmt  = (u16*)(ws + 37748736);              //    131,072
    u16* xb    = (u16*)(ws + 37879808);              // 67,108,864  residual
    char* big  = ws + 104988672;                     // transient

    // Independent chunking per phase (both divide NTOK):
    //   attn phase: qkv in-place attn -> chunk_a * 3072 B  (no attnc buffer)
    //   mlp  phase: h1             -> chunk_m * 4096 B
    const size_t fixed_bytes = 104988672ull;
    const size_t avail = (ws_size > fixed_bytes) ? (ws_size - fixed_bytes) : 0;
    int chunk_a = 8192, chunk_m = 8192;
    const int cands[3] = {65536, 32768, 16384};
    for (int i = 0; i < 3; i++)
        if ((size_t)cands[i] * 3072ull <= avail) { chunk_a = cands[i]; break; }
    for (int i = 0; i < 3; i++)
        if ((size_t)cands[i] * 4096ull <= avail) { chunk_m = cands[i]; break; }
    const int nca = NTOK / chunk_a, ncm = NTOK / chunk_m;
    u16* qkvc = (u16*)big;                           // chunk_a x 1536
    u16* h1c  = (u16*)big;                           // chunk_m x 2048

    conv_qkv2_k<<<dim3(16, 2, 144), 256, 0, stream>>>(wq, wk, wvp, wqkvt);
    conv_t2_k  <<<dim3(16, 16, 6), 256, 0, stream>>>(proj_w, wprjt, 512, 512);
    conv_t2_k  <<<dim3(64, 16, 6), 256, 0, stream>>>(w1, ww1t, 512, 2048);
    conv_t2_k  <<<dim3(16, 64, 6), 256, 0, stream>>>(w2, ww2t, 2048, 512);
    conv_lm_k  <<<128 * 512 / 256, 256, 0, stream>>>(lm_w, wlmt);

    embed_k<<<NTOK * 64 / 256, 256, 0, stream>>>(idx, tokt, post, xb);

    for (int l = 0; l < NLAYER; l++) {
        // ---- attention phase ----
        for (int c = 0; c < nca; c++) {
            const size_t t0 = (size_t)c * chunk_a;
            // qkv = x @ Wqkv
            gemm_bt<0><<<dim3(12, chunk_a / 256), 512, 0, stream>>>(
                xb + t0 * 512, wqkvt + (size_t)l * 786432, qkvc,
                nullptr, nullptr, 512, 512, 1536, 1536);
            // attention, in-place into q-slot of qkvc
            attn_k<<<chunk_a / 4, 256, 0, stream>>>(qkvc);
            // x = attno @ proj_w + proj_b + x   (A = q-slot, lda=1536)
            gemm_bt<1><<<dim3(4, chunk_a / 256), 512, 0, stream>>>(
                qkvc, wprjt + (size_t)l * 262144, xb + t0 * 512,
                proj_b + l * 512, xb + t0 * 512, 512, 1536, 512, 512);
        }
        // x = LN1(x)  (in-place)
        ln_k<<<NTOK / 4, 256, 0, stream>>>(xb, ln1_g + l * 512, ln1_b + l * 512, xb);
        // ---- MLP phase ----
        for (int c = 0; c < ncm; c++) {
            const size_t t0 = (size_t)c * chunk_m;
            // h1 = relu(x @ w1 + b1)
            gemm_bt<2><<<dim3(16, chunk_m / 256), 512, 0, stream>>>(
                xb + t0 * 512, ww1t + (size_t)l * 1048576, h1c,
                b1 + l * 2048, nullptr, 512, 512, 2048, 2048);
            // x = h1 @ w2 + b2 + x   (in-place residual)
            gemm_bt<1><<<dim3(4, chunk_m / 256), 512, 0, stream>>>(
                h1c, ww2t + (size_t)l * 1048576, xb + t0 * 512,
                b2 + l * 512, xb + t0 * 512, 2048, 2048, 512, 512);
        }
        // x = LN2(x)  (in-place)
        ln_k<<<NTOK / 4, 256, 0, stream>>>(xb, ln2_g + l * 512, ln2_b + l * 512, xb);
    }

    // logits = x @ lm_w + lm_b  (N padded to 128, masked fp32 store)
    gemm_bt<3><<<dim3(1, 256), 512, 0, stream>>>(
        xb, wlmt, out, lm_b, nullptr, 512, 512, 128, VOCAB);
}